// Round 8
// baseline (205.584 us; speedup 1.0000x reference)
//
#include <hip/hip_runtime.h>
#include <hip/hip_bf16.h>

// Problem constants
#define DIM   1024
#define NHEAD 16
#define HDIM  64
#define BATCH 2
#define SEQ   2048
#define TOK   (BATCH*SEQ)          // 4096
// q pre-scale: 64^-0.5 * log2(e)  (exp(s) == exp2(s*log2e), folded into Q)
#define QSCALE 0.1803368801111204f

typedef unsigned short u16;
typedef __attribute__((ext_vector_type(8))) _Float16 h16x8;   // 8 fp16 (4 VGPRs)
typedef __attribute__((ext_vector_type(2))) __fp16 fp16x2;    // cvt_pkrtz result
typedef __attribute__((ext_vector_type(4))) float f32x4;      // 16x16 C/D
typedef __attribute__((ext_vector_type(16))) float f32x16;    // 32x32 C/D

__device__ __forceinline__ u16 f2h(float f) {
    union { _Float16 h; u16 u; } v; v.h = (_Float16)f;        // v_cvt_f16_f32 (RNE)
    return v.u;
}
__device__ __forceinline__ unsigned pack2h(float a, float b) {
    return (unsigned)f2h(a) | ((unsigned)f2h(b) << 16);
}
__device__ __forceinline__ unsigned pkrtz(float a, float b) { // 1 VALU op
    union { fp16x2 h; unsigned u; } v;
    v.h = __builtin_amdgcn_cvt_pkrtz(a, b);
    return v.u;
}
__device__ __forceinline__ f32x16 zero16() {
    f32x16 v;
#pragma unroll
    for (int i = 0; i < 16; ++i) v[i] = 0.f;
    return v;
}

typedef __attribute__((address_space(3))) void lds_void;
typedef const __attribute__((address_space(1))) void gbl_void;
__device__ __forceinline__ void gload_lds16(const void* g, void* l) {
    __builtin_amdgcn_global_load_lds((gbl_void*)g, (lds_void*)l, 16, 0, 0);
}

// ---------------------------------------------------------------------------
// Converts (fp32 -> fp16)
// ---------------------------------------------------------------------------
__global__ __launch_bounds__(256)
void cvt_f16(const float* __restrict__ in, u16* __restrict__ out) {
    int i = blockIdx.x * 256 + threadIdx.x;          // float4 index
    float4 v = ((const float4*)in)[i];
    ((uint2*)out)[i] = make_uint2(pack2h(v.x, v.y), pack2h(v.z, v.w));
}

// in [K][N] fp32 -> out [N][K] fp16 (transposed)
__global__ __launch_bounds__(256)
void cvt_f16_T(const float* __restrict__ in, u16* __restrict__ outT,
               int K, int N) {
    __shared__ float t[32][33];
    const int n0 = blockIdx.x * 32, k0 = blockIdx.y * 32;
    const int tx = threadIdx.x & 31, ty = threadIdx.x >> 5;
#pragma unroll
    for (int i = 0; i < 4; ++i)
        t[ty + i * 8][tx] = in[(size_t)(k0 + ty + i * 8) * N + n0 + tx];
    __syncthreads();
#pragma unroll
    for (int i = 0; i < 4; ++i)
        outT[(size_t)(n0 + ty + i * 8) * K + k0 + tx] = f2h(t[tx][ty + i * 8]);
}

// ---------------------------------------------------------------------------
// QKV GEMM (fp16 MFMA): [x @ wqkv + bqkv] with per-head re-layout epilogue:
//   q (col<1024):        Qh[bh][s][d] = (acc+bias)*QSCALE  (fp16)
//   k (1024<=col<2048):  Kh[bh][s][d] = acc+bias
//   v (col>=2048):       Vh[bh][d][s] = acc+bias           (transposed)
// ---------------------------------------------------------------------------
__global__ __launch_bounds__(256)
void gemm_qkv(const u16* __restrict__ Ag, const u16* __restrict__ Bg,
              const float* __restrict__ bias, u16* __restrict__ Qh,
              u16* __restrict__ Kh, u16* __restrict__ Vh, int K, int N) {
    __shared__ u16 As[128 * 64];
    __shared__ u16 Bs[128 * 64];

    const int tid  = threadIdx.x;
    const int lane = tid & 63;
    const int w    = tid >> 6;
    const int c    = lane & 15;
    const int quad = lane >> 4;
    const int wm   = (w & 1) * 64;
    const int wn   = (w >> 1) * 64;
    const int row0 = blockIdx.y * 128;
    const int col0 = blockIdx.x * 128;
    const int sw   = c & 7;

    f32x4 acc[4][4];
#pragma unroll
    for (int m = 0; m < 4; ++m)
#pragma unroll
        for (int n = 0; n < 4; ++n) acc[m][n] = (f32x4){0.f, 0.f, 0.f, 0.f};

    for (int k0 = 0; k0 < K; k0 += 64) {
        __syncthreads();
#pragma unroll
        for (int i = 0; i < 4; ++i) {
            int idx = tid + i * 256;
            int r = idx >> 3, p = idx & 7;
            int g = p ^ (r & 7);
            gload_lds16(Ag + (size_t)(row0 + r) * K + k0 + g * 8, &As[idx * 8]);
            gload_lds16(Bg + (size_t)(col0 + r) * K + k0 + g * 8, &Bs[idx * 8]);
        }
        __syncthreads();

        h16x8 af[4][2];
#pragma unroll
        for (int m = 0; m < 4; ++m)
#pragma unroll
            for (int kh = 0; kh < 2; ++kh)
                af[m][kh] = *(const h16x8*)&As[(wm + m * 16 + c) * 64 +
                                              ((kh * 4 + quad) ^ sw) * 8];
#pragma unroll
        for (int kh = 0; kh < 2; ++kh)
#pragma unroll
            for (int n = 0; n < 4; ++n) {
                h16x8 bf = *(const h16x8*)&Bs[(wn + n * 16 + c) * 64 +
                                              ((kh * 4 + quad) ^ sw) * 8];
#pragma unroll
                for (int m = 0; m < 4; ++m)
                    acc[m][n] = __builtin_amdgcn_mfma_f32_16x16x32_f16(
                        af[m][kh], bf, acc[m][n], 0, 0, 0);
            }
    }

#pragma unroll
    for (int n = 0; n < 4; ++n) {
        const int col = col0 + wn + n * 16 + c;
        const float bv = bias[col];
        const int h = (col >> 6) & 15, d = col & 63;
#pragma unroll
        for (int m = 0; m < 4; ++m) {
            const int rbase = row0 + wm + m * 16 + quad * 4;
            const int b = rbase >> 11, s0 = rbase & (SEQ - 1);
            const int bh = (b << 4) + h;
            if (col0 < DIM) {
#pragma unroll
                for (int r = 0; r < 4; ++r)
                    Qh[((size_t)bh * SEQ + s0 + r) * 64 + d] =
                        f2h((acc[m][n][r] + bv) * QSCALE);
            } else if (col0 < 2 * DIM) {
#pragma unroll
                for (int r = 0; r < 4; ++r)
                    Kh[((size_t)bh * SEQ + s0 + r) * 64 + d] =
                        f2h(acc[m][n][r] + bv);
            } else {
                uint2 pv = make_uint2(pack2h(acc[m][n][0] + bv, acc[m][n][1] + bv),
                                      pack2h(acc[m][n][2] + bv, acc[m][n][3] + bv));
                *(uint2*)&Vh[((size_t)bh * 64 + d) * SEQ + s0] = pv;
            }
        }
    }
}

// ---------------------------------------------------------------------------
// Out-proj GEMM (single fp16 MFMA): C[M,N] = A[M,K] @ B[N,K]^T + bias, fp32 out
// ---------------------------------------------------------------------------
__global__ __launch_bounds__(256)
void gemm_out(const u16* __restrict__ Ag, const u16* __restrict__ Bg,
              const float* __restrict__ bias, float* __restrict__ Cout,
              int M, int N, int K) {
    __shared__ u16 As[128 * 64];
    __shared__ u16 Bs[64 * 64];

    const int tid  = threadIdx.x;
    const int lane = tid & 63;
    const int w    = tid >> 6;
    const int c    = lane & 15;
    const int quad = lane >> 4;
    const int wm   = w * 32;
    const int row0 = blockIdx.y * 128;
    const int col0 = blockIdx.x * 64;
    const int sw   = c & 7;

    f32x4 acc[2][4];
#pragma unroll
    for (int m = 0; m < 2; ++m)
#pragma unroll
        for (int n = 0; n < 4; ++n) acc[m][n] = (f32x4){0.f, 0.f, 0.f, 0.f};

    for (int k0 = 0; k0 < K; k0 += 64) {
        __syncthreads();
#pragma unroll
        for (int i = 0; i < 4; ++i) {
            int idx = tid + i * 256;
            int r = idx >> 3, p = idx & 7;
            int g = p ^ (r & 7);
            gload_lds16(Ag + (size_t)(row0 + r) * K + k0 + g * 8, &As[idx * 8]);
        }
#pragma unroll
        for (int i = 0; i < 2; ++i) {
            int idx = tid + i * 256;
            int r = idx >> 3, p = idx & 7;
            int g = p ^ (r & 7);
            gload_lds16(Bg + (size_t)(col0 + r) * K + k0 + g * 8, &Bs[idx * 8]);
        }
        __syncthreads();

        h16x8 af[2][2];
#pragma unroll
        for (int m = 0; m < 2; ++m)
#pragma unroll
            for (int kh = 0; kh < 2; ++kh)
                af[m][kh] = *(const h16x8*)&As[(wm + m * 16 + c) * 64 +
                                              ((kh * 4 + quad) ^ sw) * 8];
#pragma unroll
        for (int kh = 0; kh < 2; ++kh)
#pragma unroll
            for (int n = 0; n < 4; ++n) {
                h16x8 bf = *(const h16x8*)&Bs[(n * 16 + c) * 64 +
                                              ((kh * 4 + quad) ^ sw) * 8];
#pragma unroll
                for (int m = 0; m < 2; ++m)
                    acc[m][n] = __builtin_amdgcn_mfma_f32_16x16x32_f16(
                        af[m][kh], bf, acc[m][n], 0, 0, 0);
            }
    }

#pragma unroll
    for (int n = 0; n < 4; ++n) {
        const int col = col0 + n * 16 + c;
        const float bv = bias[col];
#pragma unroll
        for (int m = 0; m < 2; ++m) {
            const int rbase = row0 + wm + m * 16 + quad * 4;
#pragma unroll
            for (int r = 0; r < 4; ++r)
                Cout[(size_t)(rbase + r) * N + col] = acc[m][n][r] + bv;
        }
    }
}

// ---------------------------------------------------------------------------
// Flash attention v5: 32x32x16 fp16 MFMA (2x FLOP per LDS byte vs 16x16x32),
// Q register-cached as B-fragments for the whole K-loop, raw v_exp_f32,
// cvt_pkrtz packing. 256 threads = 4 waves x 32 q-rows; K/V double-buffered,
// one barrier/iter.
//   Layouts (32x32x16): A[m=lane&31][k=(lane>>5)*8+j], B[k=(lane>>5)*8+j]
//   [n=lane&31], C/D col=lane&31, row=(reg&3)+8*(reg>>2)+4*(lane>>5).
//   S^T = K·Q^T (lane owns q-col = lane&31 -> scalar l, b64 P writes);
//   O^T = V^T·P^T. All LDS rows pitch 64 fp16 with chunk-XOR ch^(row&7).
// ---------------------------------------------------------------------------
__global__ __launch_bounds__(256)
void flash_attn5(const u16* __restrict__ Qg, const u16* __restrict__ Kg,
                 const u16* __restrict__ Vg, u16* __restrict__ aout) {
    __shared__ u16 Qs[128 * 64];        // [q][d]
    __shared__ u16 Ks[2][64 * 64];      // [key][d]
    __shared__ u16 Vt[2][64 * 64];      // [d][key]
    __shared__ u16 Ps[128 * 64];        // [q][key] (per-wave 32-row strips)

    const int tid  = threadIdx.x;
    const int lane = tid & 63;
    const int w    = tid >> 6;          // 0..3
    const int n32  = lane & 31;         // q column
    const int q5   = lane >> 5;         // 0/1
    const int bh   = blockIdx.y;
    const int q0   = blockIdx.x * 128;

    const u16* Qb = Qg + (size_t)bh * SEQ * 64;
    const u16* Kb = Kg + (size_t)bh * SEQ * 64;
    const u16* Vb = Vg + (size_t)bh * 64 * SEQ;

    // ---- prologue: stage Q (1024 chunks) + tile 0 of K/V (512 each) ----
    {
#pragma unroll
        for (int i = 0; i < 4; ++i) {
            int idx = tid + i * 256;
            int r = idx >> 3, p = idx & 7, g = p ^ (r & 7);
            gload_lds16(Qb + (size_t)(q0 + r) * 64 + g * 8, &Qs[idx * 8]);
        }
#pragma unroll
        for (int i = 0; i < 2; ++i) {
            int idx = tid + i * 256;
            int r = idx >> 3, p = idx & 7, g = p ^ (r & 7);
            gload_lds16(Kb + (size_t)r * 64 + g * 8, &Ks[0][idx * 8]);
            gload_lds16(Vb + (size_t)r * SEQ + g * 8, &Vt[0][idx * 8]);
        }
    }
    __syncthreads();

    const int qrow = w * 32 + n32;      // block-local q row (0..127)
    const int sw   = n32 & 7;           // == qrow&7 == key-row&7 == d-row&7
    h16x8 qb[4];                        // Q B-frags, loop-invariant
#pragma unroll
    for (int s = 0; s < 4; ++s)
        qb[s] = *(const h16x8*)&Qs[qrow * 64 + (((s * 2 + q5) ^ sw) * 8)];

    float l = 0.f;
    f32x16 o[2] = {zero16(), zero16()}; // O^T[d-tile][q]

    for (int kt = 0; kt < SEQ / 64; ++kt) {
        const int cur = kt & 1, nxt = cur ^ 1;

        // ---- stage next K/V tile ----
        if (kt < SEQ / 64 - 1) {
            const int k1 = (kt + 1) * 64;
#pragma unroll
            for (int i = 0; i < 2; ++i) {
                int idx = tid + i * 256;
                int r = idx >> 3, p = idx & 7, g = p ^ (r & 7);
                gload_lds16(Kb + (size_t)(k1 + r) * 64 + g * 8, &Ks[nxt][idx * 8]);
                gload_lds16(Vb + (size_t)r * SEQ + k1 + g * 8, &Vt[nxt][idx * 8]);
            }
        }

        // ---- S^T = K Q^T in two 32-key subtiles; exp; pack to Ps ----
#pragma unroll
        for (int sub = 0; sub < 2; ++sub) {
            const int kr = sub * 32 + n32;          // key row (kr&7 == sw)
            f32x16 sa = zero16();
#pragma unroll
            for (int s = 0; s < 4; ++s) {
                h16x8 ak = *(const h16x8*)&Ks[cur][kr * 64 +
                                                   (((s * 2 + q5) ^ sw) * 8)];
                sa = __builtin_amdgcn_mfma_f32_32x32x16_f16(ak, qb[s], sa, 0, 0, 0);
            }
#pragma unroll
            for (int r = 0; r < 4; ++r) {
                float p0 = __builtin_amdgcn_exp2f(sa[4 * r + 0]);
                float p1 = __builtin_amdgcn_exp2f(sa[4 * r + 1]);
                float p2 = __builtin_amdgcn_exp2f(sa[4 * r + 2]);
                float p3 = __builtin_amdgcn_exp2f(sa[4 * r + 3]);
                l += (p0 + p1) + (p2 + p3);
                const int ch = sub * 4 + r;         // keys sub*32+8r+4q5+0..3
                *(uint2*)&Ps[qrow * 64 + ((ch ^ sw) * 8 + 4 * q5)] =
                    make_uint2(pkrtz(p0, p1), pkrtz(p2, p3));
            }
        }

        // ---- O^T += V^T P^T (P round-trip within wave, lgkmcnt-ordered) ----
        h16x8 bp[4];
#pragma unroll
        for (int s = 0; s < 4; ++s)
            bp[s] = *(const h16x8*)&Ps[qrow * 64 + (((s * 2 + q5) ^ sw) * 8)];
#pragma unroll
        for (int dt = 0; dt < 2; ++dt) {
            const int dr = dt * 32 + n32;           // d row (dr&7 == sw)
#pragma unroll
            for (int s = 0; s < 4; ++s) {
                h16x8 av = *(const h16x8*)&Vt[cur][dr * 64 +
                                                   (((s * 2 + q5) ^ sw) * 8)];
                o[dt] = __builtin_amdgcn_mfma_f32_32x32x16_f16(av, bp[s], o[dt], 0, 0, 0);
            }
        }

        __syncthreads();   // cur readers done + nxt staged
    }

    // ---- l: other q5-half holds the remaining keys for the same q ----
    l += __shfl_xor(l, 32, 64);
    const float inv = 1.f / l;

    const int b = bh >> 4, h = bh & 15;
    const size_t ro = (size_t)(b * SEQ + q0 + qrow) * DIM + h * HDIM;
#pragma unroll
    for (int dt = 0; dt < 2; ++dt) {
#pragma unroll
        for (int rq = 0; rq < 4; ++rq) {
            const int d = dt * 32 + 8 * rq + 4 * q5;
            *(uint2*)&aout[ro + d] = make_uint2(
                pkrtz(o[dt][4 * rq + 0] * inv, o[dt][4 * rq + 1] * inv),
                pkrtz(o[dt][4 * rq + 2] * inv, o[dt][4 * rq + 3] * inv));
        }
    }
}

// ---------------------------------------------------------------------------
extern "C" void kernel_launch(void* const* d_in, const int* in_sizes, int n_in,
                              void* d_out, int out_size, void* d_ws, size_t ws_size,
                              hipStream_t stream) {
    (void)in_sizes; (void)n_in; (void)out_size; (void)ws_size;
    const float* x    = (const float*)d_in[0];   // [4096,1024]
    const float* wqkv = (const float*)d_in[1];   // [1024,3072]
    const float* bqkv = (const float*)d_in[2];   // [3072]
    const float* wo   = (const float*)d_in[3];   // [1024,1024]
    const float* bo   = (const float*)d_in[4];   // [1024]
    float* out = (float*)d_out;                  // [4096,1024] fp32

    // workspace (48 MB)
    const size_t HB = (size_t)BATCH * NHEAD * SEQ * HDIM;   // 4M elems
    u16* Qh  = (u16*)d_ws;                       // [32][2048][64]
    u16* Kh  = Qh + HB;                          // [32][2048][64]
    u16* Vh  = Kh + HB;                          // [32][64][2048]
    u16* ao  = Vh + HB;                          // attn out fp16 [4096][1024]
    u16* wqT = ao + (size_t)TOK * DIM;           // wqkv^T fp16 [3072][1024]
    u16* woT = wqT + (size_t)3 * DIM * DIM;      // wo^T fp16 [1024][1024]
    u16* xh  = woT + (size_t)DIM * DIM;          // x fp16 [4096][1024]

    // 1) converts
    cvt_f16<<<TOK * DIM / 4 / 256, 256, 0, stream>>>(x, xh);
    cvt_f16_T<<<dim3(3 * DIM / 32, DIM / 32), 256, 0, stream>>>(wqkv, wqT, DIM, 3 * DIM);
    cvt_f16_T<<<dim3(DIM / 32, DIM / 32), 256, 0, stream>>>(wo, woT, DIM, DIM);
    // 2) qkv GEMM with per-head re-layout epilogue
    gemm_qkv<<<dim3(3 * DIM / 128, TOK / 128), 256, 0, stream>>>(
        xh, wqT, bqkv, Qh, Kh, Vh, DIM, 3 * DIM);
    // 3) attention -> fp16 out (32x32 MFMA)
    flash_attn5<<<dim3(SEQ / 128, BATCH * NHEAD), 256, 0, stream>>>(
        Qh, Kh, Vh, ao);
    // 4) out = attn @ wo + bo (fp32 out)
    gemm_out<<<dim3(DIM / 64, TOK / 128), 256, 0, stream>>>(
        ao, woT, bo, out, TOK, DIM, DIM);
}

// Round 10
// 195.960 us; speedup vs baseline: 1.0491x; 1.0491x over previous
//
#include <hip/hip_runtime.h>
#include <hip/hip_bf16.h>

// Problem constants
#define DIM   1024
#define NHEAD 16
#define HDIM  64
#define BATCH 2
#define SEQ   2048
#define TOK   (BATCH*SEQ)          // 4096
// q pre-scale: 64^-0.5 * log2(e)  (exp(s) == exp2(s*log2e), folded into Q)
#define QSCALE 0.1803368801111204f

typedef unsigned short u16;
typedef __attribute__((ext_vector_type(8))) _Float16 h16x8;   // 8 fp16 (4 VGPRs)
typedef __attribute__((ext_vector_type(2))) __fp16 fp16x2;    // cvt_pkrtz result
typedef __attribute__((ext_vector_type(4))) float f32x4;      // 16x16 C/D
typedef __attribute__((ext_vector_type(16))) float f32x16;    // 32x32 C/D

__device__ __forceinline__ u16 f2h(float f) {
    union { _Float16 h; u16 u; } v; v.h = (_Float16)f;        // v_cvt_f16_f32 (RNE)
    return v.u;
}
__device__ __forceinline__ unsigned pack2h(float a, float b) {
    return (unsigned)f2h(a) | ((unsigned)f2h(b) << 16);
}
__device__ __forceinline__ unsigned pkrtz(float a, float b) { // 1 VALU op
    union { fp16x2 h; unsigned u; } v;
    v.h = __builtin_amdgcn_cvt_pkrtz(a, b);
    return v.u;
}
__device__ __forceinline__ f32x16 zero16() {
    f32x16 v;
#pragma unroll
    for (int i = 0; i < 16; ++i) v[i] = 0.f;
    return v;
}

typedef __attribute__((address_space(3))) void lds_void;
typedef const __attribute__((address_space(1))) void gbl_void;
__device__ __forceinline__ void gload_lds16(const void* g, void* l) {
    __builtin_amdgcn_global_load_lds((gbl_void*)g, (lds_void*)l, 16, 0, 0);
}

// ---------------------------------------------------------------------------
// Converts (fp32 -> fp16)
// ---------------------------------------------------------------------------
__global__ __launch_bounds__(256)
void cvt_f16(const float* __restrict__ in, u16* __restrict__ out) {
    int i = blockIdx.x * 256 + threadIdx.x;          // float4 index
    float4 v = ((const float4*)in)[i];
    ((uint2*)out)[i] = make_uint2(pack2h(v.x, v.y), pack2h(v.z, v.w));
}

// in [K][N] fp32 -> out [N][K] fp16 (transposed)
__global__ __launch_bounds__(256)
void cvt_f16_T(const float* __restrict__ in, u16* __restrict__ outT,
               int K, int N) {
    __shared__ float t[32][33];
    const int n0 = blockIdx.x * 32, k0 = blockIdx.y * 32;
    const int tx = threadIdx.x & 31, ty = threadIdx.x >> 5;
#pragma unroll
    for (int i = 0; i < 4; ++i)
        t[ty + i * 8][tx] = in[(size_t)(k0 + ty + i * 8) * N + n0 + tx];
    __syncthreads();
#pragma unroll
    for (int i = 0; i < 4; ++i)
        outT[(size_t)(n0 + ty + i * 8) * K + k0 + tx] = f2h(t[tx][ty + i * 8]);
}

// ---------------------------------------------------------------------------
// QKV GEMM (fp16 MFMA): [x @ wqkv + bqkv] with per-head re-layout epilogue:
//   q (col<1024):        Qh[bh][s][d] = (acc+bias)*QSCALE  (fp16)
//   k (1024<=col<2048):  Kh[bh][s][d] = acc+bias
//   v (col>=2048):       Vh[bh][d][s] = acc+bias           (transposed)
// ---------------------------------------------------------------------------
__global__ __launch_bounds__(256)
void gemm_qkv(const u16* __restrict__ Ag, const u16* __restrict__ Bg,
              const float* __restrict__ bias, u16* __restrict__ Qh,
              u16* __restrict__ Kh, u16* __restrict__ Vh, int K, int N) {
    __shared__ u16 As[128 * 64];
    __shared__ u16 Bs[128 * 64];

    const int tid  = threadIdx.x;
    const int lane = tid & 63;
    const int w    = tid >> 6;
    const int c    = lane & 15;
    const int quad = lane >> 4;
    const int wm   = (w & 1) * 64;
    const int wn   = (w >> 1) * 64;
    const int row0 = blockIdx.y * 128;
    const int col0 = blockIdx.x * 128;
    const int sw   = c & 7;

    f32x4 acc[4][4];
#pragma unroll
    for (int m = 0; m < 4; ++m)
#pragma unroll
        for (int n = 0; n < 4; ++n) acc[m][n] = (f32x4){0.f, 0.f, 0.f, 0.f};

    for (int k0 = 0; k0 < K; k0 += 64) {
        __syncthreads();
#pragma unroll
        for (int i = 0; i < 4; ++i) {
            int idx = tid + i * 256;
            int r = idx >> 3, p = idx & 7;
            int g = p ^ (r & 7);
            gload_lds16(Ag + (size_t)(row0 + r) * K + k0 + g * 8, &As[idx * 8]);
            gload_lds16(Bg + (size_t)(col0 + r) * K + k0 + g * 8, &Bs[idx * 8]);
        }
        __syncthreads();

        h16x8 af[4][2];
#pragma unroll
        for (int m = 0; m < 4; ++m)
#pragma unroll
            for (int kh = 0; kh < 2; ++kh)
                af[m][kh] = *(const h16x8*)&As[(wm + m * 16 + c) * 64 +
                                              ((kh * 4 + quad) ^ sw) * 8];
#pragma unroll
        for (int kh = 0; kh < 2; ++kh)
#pragma unroll
            for (int n = 0; n < 4; ++n) {
                h16x8 bf = *(const h16x8*)&Bs[(wn + n * 16 + c) * 64 +
                                              ((kh * 4 + quad) ^ sw) * 8];
#pragma unroll
                for (int m = 0; m < 4; ++m)
                    acc[m][n] = __builtin_amdgcn_mfma_f32_16x16x32_f16(
                        af[m][kh], bf, acc[m][n], 0, 0, 0);
            }
    }

#pragma unroll
    for (int n = 0; n < 4; ++n) {
        const int col = col0 + wn + n * 16 + c;
        const float bv = bias[col];
        const int h = (col >> 6) & 15, d = col & 63;
#pragma unroll
        for (int m = 0; m < 4; ++m) {
            const int rbase = row0 + wm + m * 16 + quad * 4;
            const int b = rbase >> 11, s0 = rbase & (SEQ - 1);
            const int bh = (b << 4) + h;
            if (col0 < DIM) {
#pragma unroll
                for (int r = 0; r < 4; ++r)
                    Qh[((size_t)bh * SEQ + s0 + r) * 64 + d] =
                        f2h((acc[m][n][r] + bv) * QSCALE);
            } else if (col0 < 2 * DIM) {
#pragma unroll
                for (int r = 0; r < 4; ++r)
                    Kh[((size_t)bh * SEQ + s0 + r) * 64 + d] =
                        f2h(acc[m][n][r] + bv);
            } else {
                uint2 pv = make_uint2(pack2h(acc[m][n][0] + bv, acc[m][n][1] + bv),
                                      pack2h(acc[m][n][2] + bv, acc[m][n][3] + bv));
                *(uint2*)&Vh[((size_t)bh * 64 + d) * SEQ + s0] = pv;
            }
        }
    }
}

// ---------------------------------------------------------------------------
// Out-proj GEMM (single fp16 MFMA): C[M,N] = A[M,K] @ B[N,K]^T + bias, fp32 out
// ---------------------------------------------------------------------------
__global__ __launch_bounds__(256)
void gemm_out(const u16* __restrict__ Ag, const u16* __restrict__ Bg,
              const float* __restrict__ bias, float* __restrict__ Cout,
              int M, int N, int K) {
    __shared__ u16 As[128 * 64];
    __shared__ u16 Bs[64 * 64];

    const int tid  = threadIdx.x;
    const int lane = tid & 63;
    const int w    = tid >> 6;
    const int c    = lane & 15;
    const int quad = lane >> 4;
    const int wm   = w * 32;
    const int row0 = blockIdx.y * 128;
    const int col0 = blockIdx.x * 64;
    const int sw   = c & 7;

    f32x4 acc[2][4];
#pragma unroll
    for (int m = 0; m < 2; ++m)
#pragma unroll
        for (int n = 0; n < 4; ++n) acc[m][n] = (f32x4){0.f, 0.f, 0.f, 0.f};

    for (int k0 = 0; k0 < K; k0 += 64) {
        __syncthreads();
#pragma unroll
        for (int i = 0; i < 4; ++i) {
            int idx = tid + i * 256;
            int r = idx >> 3, p = idx & 7;
            int g = p ^ (r & 7);
            gload_lds16(Ag + (size_t)(row0 + r) * K + k0 + g * 8, &As[idx * 8]);
        }
#pragma unroll
        for (int i = 0; i < 2; ++i) {
            int idx = tid + i * 256;
            int r = idx >> 3, p = idx & 7;
            int g = p ^ (r & 7);
            gload_lds16(Bg + (size_t)(col0 + r) * K + k0 + g * 8, &Bs[idx * 8]);
        }
        __syncthreads();

        h16x8 af[2][2];
#pragma unroll
        for (int m = 0; m < 2; ++m)
#pragma unroll
            for (int kh = 0; kh < 2; ++kh)
                af[m][kh] = *(const h16x8*)&As[(wm + m * 16 + c) * 64 +
                                              ((kh * 4 + quad) ^ sw) * 8];
#pragma unroll
        for (int kh = 0; kh < 2; ++kh)
#pragma unroll
            for (int n = 0; n < 4; ++n) {
                h16x8 bf = *(const h16x8*)&Bs[(n * 16 + c) * 64 +
                                              ((kh * 4 + quad) ^ sw) * 8];
#pragma unroll
                for (int m = 0; m < 2; ++m)
                    acc[m][n] = __builtin_amdgcn_mfma_f32_16x16x32_f16(
                        af[m][kh], bf, acc[m][n], 0, 0, 0);
            }
    }

#pragma unroll
    for (int n = 0; n < 4; ++n) {
        const int col = col0 + n * 16 + c;
        const float bv = bias[col];
#pragma unroll
        for (int m = 0; m < 2; ++m) {
            const int rbase = row0 + wm + m * 16 + quad * 4;
#pragma unroll
            for (int r = 0; r < 4; ++r)
                Cout[(size_t)(rbase + r) * N + col] = acc[m][n][r] + bv;
        }
    }
}

// ---------------------------------------------------------------------------
// Flash attention v7: r8's proven 32x32x16 structure + __syncthreads sync,
// but BK=128: two 64-key subtiles per barrier (halves barrier count, doubles
// the load-landing window covered by each drain). Numerics identical to r8.
//   K buf [2][128 keys][64 d], V buf [2][64 d][128 keys] (fp16, XOR-swizzled
//   16B chunks: stored pos = chunk ^ (row&7), low-3-bit XOR only).
//   Ps overlays dead Q-staging LDS (per-wave-private 32-row strips).
// 256 threads = 4 waves x 32 q-rows. LDS 80 KB -> 2 blocks/CU.
// ---------------------------------------------------------------------------
__global__ __launch_bounds__(256)
void flash_attn7(const u16* __restrict__ Qg, const u16* __restrict__ Kg,
                 const u16* __restrict__ Vg, u16* __restrict__ aout) {
    __shared__ u16 QPs[128 * 64];       // Q staging, then P strips (16 KB)
    __shared__ u16 Ks[2][128 * 64];     // [key][d]   (32 KB)
    __shared__ u16 Vt[2][64 * 128];     // [d][key]   (32 KB)

    const int tid  = threadIdx.x;
    const int lane = tid & 63;
    const int w    = tid >> 6;          // 0..3
    const int n32  = lane & 31;         // q column
    const int q5   = lane >> 5;         // 0/1
    const int bh   = blockIdx.y;
    const int q0   = blockIdx.x * 128;

    const u16* Qb = Qg + (size_t)bh * SEQ * 64;
    const u16* Kb = Kg + (size_t)bh * SEQ * 64;
    const u16* Vb = Vg + (size_t)bh * 64 * SEQ;

    // ---- prologue: stage Q (4 loads) + 128-key tile 0 (8 loads) ----
#pragma unroll
    for (int i = 0; i < 4; ++i) {
        int idx = tid + i * 256;
        int r = idx >> 3, p = idx & 7, g = p ^ (r & 7);
        gload_lds16(Qb + (size_t)(q0 + r) * 64 + g * 8, &QPs[idx * 8]);
    }
#pragma unroll
    for (int i = 0; i < 4; ++i) {
        int idx = tid + i * 256;
        int rk = idx >> 3, pk = idx & 7, gk = pk ^ (rk & 7);
        gload_lds16(Kb + (size_t)rk * 64 + gk * 8, &Ks[0][idx * 8]);
        int rv = idx >> 4, cv = idx & 15, gv = cv ^ (rv & 7);
        gload_lds16(Vb + (size_t)rv * SEQ + gv * 8, &Vt[0][idx * 8]);
    }
    __syncthreads();

    const int qrow = w * 32 + n32;      // block-local q row (0..127)
    const int sw   = n32 & 7;           // == qrow&7 == key-row&7 == d-row&7
    h16x8 qb[4];                        // Q B-frags, loop-invariant
#pragma unroll
    for (int s = 0; s < 4; ++s)
        qb[s] = *(const h16x8*)&QPs[qrow * 64 + (((s * 2 + q5) ^ sw) * 8)];
    // (Ps writes below hit only this wave's own rows -> overlay is safe)

    float l = 0.f;
    f32x16 o[2] = {zero16(), zero16()}; // O^T[d-tile][q]

    for (int kt = 0; kt < SEQ / 128; ++kt) {
        const int cur = kt & 1, nxt = cur ^ 1;

        // ---- stage next 128-key tile (loads fly during 2-subtile compute) ----
        if (kt < SEQ / 128 - 1) {
            const int k1 = (kt + 1) * 128;
#pragma unroll
            for (int i = 0; i < 4; ++i) {
                int idx = tid + i * 256;
                int rk = idx >> 3, pk = idx & 7, gk = pk ^ (rk & 7);
                gload_lds16(Kb + (size_t)(k1 + rk) * 64 + gk * 8, &Ks[nxt][idx * 8]);
                int rv = idx >> 4, cv = idx & 15, gv = cv ^ (rv & 7);
                gload_lds16(Vb + (size_t)rv * SEQ + k1 + gv * 8, &Vt[nxt][idx * 8]);
            }
        }

        // ---- two 64-key subtiles, sequential through the same P strip ----
#pragma unroll
        for (int sub2 = 0; sub2 < 2; ++sub2) {
            // S^T = K Q^T in two 32-key halves; exp; pack to Ps
#pragma unroll
            for (int sub = 0; sub < 2; ++sub) {
                const int kr = sub2 * 64 + sub * 32 + n32;   // kr&7 == sw
                f32x16 sa = zero16();
#pragma unroll
                for (int s = 0; s < 4; ++s) {
                    h16x8 ak = *(const h16x8*)&Ks[cur][kr * 64 +
                                                       (((s * 2 + q5) ^ sw) * 8)];
                    sa = __builtin_amdgcn_mfma_f32_32x32x16_f16(ak, qb[s], sa, 0, 0, 0);
                }
#pragma unroll
                for (int r = 0; r < 4; ++r) {
                    float p0 = __builtin_amdgcn_exp2f(sa[4 * r + 0]);
                    float p1 = __builtin_amdgcn_exp2f(sa[4 * r + 1]);
                    float p2 = __builtin_amdgcn_exp2f(sa[4 * r + 2]);
                    float p3 = __builtin_amdgcn_exp2f(sa[4 * r + 3]);
                    l += (p0 + p1) + (p2 + p3);
                    const int ch = sub * 4 + r;     // keys sub*32+8r+4q5+0..3
                    *(uint2*)&QPs[qrow * 64 + ((ch ^ sw) * 8 + 4 * q5)] =
                        make_uint2(pkrtz(p0, p1), pkrtz(p2, p3));
                }
            }

            // O^T += V^T P^T (same-wave LDS round trip, lgkmcnt-ordered)
            h16x8 bp[4];
#pragma unroll
            for (int s = 0; s < 4; ++s)
                bp[s] = *(const h16x8*)&QPs[qrow * 64 + (((s * 2 + q5) ^ sw) * 8)];
#pragma unroll
            for (int dt = 0; dt < 2; ++dt) {
                const int dr = dt * 32 + n32;       // dr&7 == sw
#pragma unroll
                for (int s = 0; s < 4; ++s) {
                    h16x8 av = *(const h16x8*)&Vt[cur][dr * 128 +
                                                       ((sub2 * 8 + ((s * 2 + q5) ^ sw)) * 8)];
                    o[dt] = __builtin_amdgcn_mfma_f32_32x32x16_f16(av, bp[s], o[dt], 0, 0, 0);
                }
            }
        }

        __syncthreads();   // cur readers done + nxt staged (vmcnt drain)
    }

    // ---- l: other q5-half holds the remaining keys for the same q ----
    l += __shfl_xor(l, 32, 64);
    const float inv = 1.f / l;

    const int b = bh >> 4, h = bh & 15;
    const size_t ro = (size_t)(b * SEQ + q0 + qrow) * DIM + h * HDIM;
#pragma unroll
    for (int dt = 0; dt < 2; ++dt) {
#pragma unroll
        for (int rq = 0; rq < 4; ++rq) {
            const int d = dt * 32 + 8 * rq + 4 * q5;
            *(uint2*)&aout[ro + d] = make_uint2(
                pkrtz(o[dt][4 * rq + 0] * inv, o[dt][4 * rq + 1] * inv),
                pkrtz(o[dt][4 * rq + 2] * inv, o[dt][4 * rq + 3] * inv));
        }
    }
}

// ---------------------------------------------------------------------------
extern "C" void kernel_launch(void* const* d_in, const int* in_sizes, int n_in,
                              void* d_out, int out_size, void* d_ws, size_t ws_size,
                              hipStream_t stream) {
    (void)in_sizes; (void)n_in; (void)out_size; (void)ws_size;
    const float* x    = (const float*)d_in[0];   // [4096,1024]
    const float* wqkv = (const float*)d_in[1];   // [1024,3072]
    const float* bqkv = (const float*)d_in[2];   // [3072]
    const float* wo   = (const float*)d_in[3];   // [1024,1024]
    const float* bo   = (const float*)d_in[4];   // [1024]
    float* out = (float*)d_out;                  // [4096,1024] fp32

    // workspace (48 MB)
    const size_t HB = (size_t)BATCH * NHEAD * SEQ * HDIM;   // 4M elems
    u16* Qh  = (u16*)d_ws;                       // [32][2048][64]
    u16* Kh  = Qh + HB;                          // [32][2048][64]
    u16* Vh  = Kh + HB;                          // [32][64][2048]
    u16* ao  = Vh + HB;                          // attn out fp16 [4096][1024]
    u16* wqT = ao + (size_t)TOK * DIM;           // wqkv^T fp16 [3072][1024]
    u16* woT = wqT + (size_t)3 * DIM * DIM;      // wo^T fp16 [1024][1024]
    u16* xh  = woT + (size_t)DIM * DIM;          // x fp16 [4096][1024]

    // 1) converts
    cvt_f16<<<TOK * DIM / 4 / 256, 256, 0, stream>>>(x, xh);
    cvt_f16_T<<<dim3(3 * DIM / 32, DIM / 32), 256, 0, stream>>>(wqkv, wqT, DIM, 3 * DIM);
    cvt_f16_T<<<dim3(DIM / 32, DIM / 32), 256, 0, stream>>>(wo, woT, DIM, DIM);
    // 2) qkv GEMM with per-head re-layout epilogue
    gemm_qkv<<<dim3(3 * DIM / 128, TOK / 128), 256, 0, stream>>>(
        xh, wqT, bqkv, Qh, Kh, Vh, DIM, 3 * DIM);
    // 3) attention -> fp16 out (32x32 MFMA, BK=128 double-buffer)
    flash_attn7<<<dim3(SEQ / 128, BATCH * NHEAD), 256, 0, stream>>>(
        Qh, Kh, Vh, ao);
    // 4) out = attn @ wo + bo (fp32 out)
    gemm_out<<<dim3(DIM / 64, TOK / 128), 256, 0, stream>>>(
        ao, woT, bo, out, TOK, DIM, DIM);
}